// Round 3
// baseline (2226.817 us; speedup 1.0000x reference)
//
#include <hip/hip_runtime.h>

#define N_NODES 50000
#define N_EDGES 800000
#define IN_DIM 16
#define HID 16
#define EDGE_DIM 8
#define GRAPH_DIM 8
#define N_LAYERS 3

// ---------------------------------------------------------------------------
// prep: one thread per (node, o). Computes, for one layer:
//   z[n][k][o]  = sum_i x[n][i] * nnW[k][i*16+o]        (k = 0..7)
//   w[n][o]     = sum_i x[n][i] * nnb[i*16+o]
//   agg[n][o]   = bias[o] + sum_i x[n][i] * rootW[i][o]   (scatter init)
// x read applies ReLU when reading a previous layer's pre-activation agg.
// ---------------------------------------------------------------------------
__global__ __launch_bounds__(256)
void prep_kernel(const float* __restrict__ x_in,   // [N,16]
                 const float* __restrict__ nnW,    // [8,256]
                 const float* __restrict__ nnb,    // [256]
                 const float* __restrict__ rootW,  // [16,16]
                 const float* __restrict__ bias,   // [16]
                 float* __restrict__ z,            // [N,8,16]
                 float* __restrict__ w,            // [N,16]
                 float* __restrict__ agg,          // [N,16]
                 int apply_relu) {
    int t = blockIdx.x * blockDim.x + threadIdx.x;
    if (t >= N_NODES * HID) return;
    int n = t >> 4;
    int o = t & 15;

    float xv[IN_DIM];
    const float* xr = x_in + n * IN_DIM;
#pragma unroll
    for (int i = 0; i < IN_DIM; ++i) {
        float v = xr[i];
        xv[i] = apply_relu ? fmaxf(v, 0.0f) : v;
    }

    float zk[EDGE_DIM];
#pragma unroll
    for (int k = 0; k < EDGE_DIM; ++k) zk[k] = 0.0f;
    float wv = 0.0f;
    float rv = bias[o];

#pragma unroll
    for (int i = 0; i < IN_DIM; ++i) {
        float xi = xv[i];
#pragma unroll
        for (int k = 0; k < EDGE_DIM; ++k) {
            zk[k] = fmaf(xi, nnW[k * 256 + i * 16 + o], zk[k]);
        }
        wv = fmaf(xi, nnb[i * 16 + o], wv);
        rv = fmaf(xi, rootW[i * 16 + o], rv);
    }

    float* zn = z + n * (EDGE_DIM * HID);
#pragma unroll
    for (int k = 0; k < EDGE_DIM; ++k) zn[k * 16 + o] = zk[k];
    w[n * 16 + o] = wv;
    agg[n * 16 + o] = rv;
}

// ---------------------------------------------------------------------------
// edge: one thread per edge.
//   msg[o] = w[src][o] + sum_k ea[e][k] * z[src][k][o]
//   atomicAdd(agg[dst][o], msg[o])
// ---------------------------------------------------------------------------
__global__ __launch_bounds__(256)
void edge_kernel(const int* __restrict__ ei,      // [2,E]
                 const float* __restrict__ ea,    // [E,8]
                 const float* __restrict__ z,     // [N,8,16]
                 const float* __restrict__ w,     // [N,16]
                 float* __restrict__ agg) {       // [N,16]
    int e = blockIdx.x * blockDim.x + threadIdx.x;
    if (e >= N_EDGES) return;
    int src = ei[e];
    int dst = ei[N_EDGES + e];

    const float4* eap = (const float4*)(ea + e * EDGE_DIM);
    float4 ea0 = eap[0];
    float4 ea1 = eap[1];
    float eav[EDGE_DIM] = {ea0.x, ea0.y, ea0.z, ea0.w, ea1.x, ea1.y, ea1.z, ea1.w};

    const float4* wp = (const float4*)(w + src * HID);
    float4 m0 = wp[0], m1 = wp[1], m2 = wp[2], m3 = wp[3];

    const float4* zp = (const float4*)(z + src * (EDGE_DIM * HID));
#pragma unroll
    for (int k = 0; k < EDGE_DIM; ++k) {
        float a = eav[k];
        float4 z0 = zp[k * 4 + 0];
        float4 z1 = zp[k * 4 + 1];
        float4 z2 = zp[k * 4 + 2];
        float4 z3 = zp[k * 4 + 3];
        m0.x = fmaf(a, z0.x, m0.x); m0.y = fmaf(a, z0.y, m0.y);
        m0.z = fmaf(a, z0.z, m0.z); m0.w = fmaf(a, z0.w, m0.w);
        m1.x = fmaf(a, z1.x, m1.x); m1.y = fmaf(a, z1.y, m1.y);
        m1.z = fmaf(a, z1.z, m1.z); m1.w = fmaf(a, z1.w, m1.w);
        m2.x = fmaf(a, z2.x, m2.x); m2.y = fmaf(a, z2.y, m2.y);
        m2.z = fmaf(a, z2.z, m2.z); m2.w = fmaf(a, z2.w, m2.w);
        m3.x = fmaf(a, z3.x, m3.x); m3.y = fmaf(a, z3.y, m3.y);
        m3.z = fmaf(a, z3.z, m3.z); m3.w = fmaf(a, z3.w, m3.w);
    }

    float* ad = agg + dst * HID;
    atomicAdd(&ad[0],  m0.x); atomicAdd(&ad[1],  m0.y);
    atomicAdd(&ad[2],  m0.z); atomicAdd(&ad[3],  m0.w);
    atomicAdd(&ad[4],  m1.x); atomicAdd(&ad[5],  m1.y);
    atomicAdd(&ad[6],  m1.z); atomicAdd(&ad[7],  m1.w);
    atomicAdd(&ad[8],  m2.x); atomicAdd(&ad[9],  m2.y);
    atomicAdd(&ad[10], m2.z); atomicAdd(&ad[11], m2.w);
    atomicAdd(&ad[12], m3.x); atomicAdd(&ad[13], m3.y);
    atomicAdd(&ad[14], m3.z); atomicAdd(&ad[15], m3.w);
}

// ---------------------------------------------------------------------------
// head: one thread per node.
//   out[n] = head_b + sum_o relu(agg[n][o]) * head_W[o]
//                   + sum_g gf[g][n] * head_W[16+g]
// ---------------------------------------------------------------------------
__global__ __launch_bounds__(256)
void head_kernel(const float* __restrict__ agg,   // [N,16] pre-ReLU
                 const float* __restrict__ gf,    // [8,N]
                 const float* __restrict__ hW,    // [24,1]
                 const float* __restrict__ hb,    // [1]
                 float* __restrict__ out) {       // [N]
    int n = blockIdx.x * blockDim.x + threadIdx.x;
    if (n >= N_NODES) return;
    float acc = hb[0];
    const float* ar = agg + n * HID;
#pragma unroll
    for (int o = 0; o < HID; ++o) acc = fmaf(fmaxf(ar[o], 0.0f), hW[o], acc);
#pragma unroll
    for (int g = 0; g < GRAPH_DIM; ++g) acc = fmaf(gf[g * N_NODES + n], hW[HID + g], acc);
    out[n] = acc;
}

extern "C" void kernel_launch(void* const* d_in, const int* in_sizes, int n_in,
                              void* d_out, int out_size, void* d_ws, size_t ws_size,
                              hipStream_t stream) {
    const float* x     = (const float*)d_in[0];
    const int*   ei    = (const int*)d_in[1];
    const float* ea    = (const float*)d_in[2];
    const float* gf    = (const float*)d_in[3];
    const float* nnW   = (const float*)d_in[4];
    const float* nnb   = (const float*)d_in[5];
    const float* rootW = (const float*)d_in[6];
    const float* bias  = (const float*)d_in[7];
    const float* hW    = (const float*)d_in[8];
    const float* hb    = (const float*)d_in[9];
    float* out = (float*)d_out;

    // workspace layout (all f32):
    //   z:    N*128  = 25.6 MB
    //   w:    N*16   =  3.2 MB
    //   aggA: N*16   =  3.2 MB
    //   aggB: N*16   =  3.2 MB   (total 35.2 MB)
    float* z    = (float*)d_ws;
    float* w    = z + (size_t)N_NODES * 128;
    float* aggA = w + (size_t)N_NODES * 16;
    float* aggB = aggA + (size_t)N_NODES * 16;

    dim3 blk(256);
    dim3 grid_no((N_NODES * HID + 255) / 256);   // prep: thread per (n,o)
    dim3 grid_e((N_EDGES + 255) / 256);          // edge: thread per edge
    dim3 grid_n((N_NODES + 255) / 256);          // head: thread per node

    const float* xin = x;
    float* aggs[2] = {aggA, aggB};
    for (int l = 0; l < N_LAYERS; ++l) {
        float* agg = aggs[l & 1];
        prep_kernel<<<grid_no, blk, 0, stream>>>(
            xin,
            nnW + (size_t)l * EDGE_DIM * (IN_DIM * HID),
            nnb + (size_t)l * (IN_DIM * HID),
            rootW + (size_t)l * IN_DIM * HID,
            bias + (size_t)l * HID,
            z, w, agg, l > 0 ? 1 : 0);
        edge_kernel<<<grid_e, blk, 0, stream>>>(ei, ea, z, w, agg);
        xin = agg;
    }
    // after 3 layers xin == aggA (l=0:A, l=1:B, l=2:A)
    head_kernel<<<grid_n, blk, 0, stream>>>(xin, gf, hW, hb, out);
}

// Round 4
// 515.260 us; speedup vs baseline: 4.3217x; 4.3217x over previous
//
#include <hip/hip_runtime.h>

#define N_NODES 50000
#define N_EDGES 800000
#define IN_DIM 16
#define HID 16
#define EDGE_DIM 8
#define GRAPH_DIM 8
#define N_LAYERS 3
#define SCAN_BS 256
#define SCAN_NB ((N_NODES + SCAN_BS - 1) / SCAN_BS)   // 196

// ---------------------------------------------------------------------------
// CSR build (once per launch; edge_index is layer-invariant)
// ---------------------------------------------------------------------------
__global__ __launch_bounds__(256)
void zero_deg_kernel(int* __restrict__ deg) {
    int i = blockIdx.x * blockDim.x + threadIdx.x;
    if (i < N_NODES) deg[i] = 0;
}

__global__ __launch_bounds__(256)
void hist_kernel(const int* __restrict__ ei, int* __restrict__ deg) {
    int e = blockIdx.x * blockDim.x + threadIdx.x;
    if (e < N_EDGES) atomicAdd(&deg[ei[N_EDGES + e]], 1);
}

// exclusive block-scan of deg -> offs (local), block totals -> bsum
__global__ __launch_bounds__(SCAN_BS)
void scan1_kernel(const int* __restrict__ deg, int* __restrict__ offs,
                  int* __restrict__ bsum) {
    __shared__ int s[SCAN_BS];
    int tid = threadIdx.x;
    int i = blockIdx.x * SCAN_BS + tid;
    int v = (i < N_NODES) ? deg[i] : 0;
    s[tid] = v;
    __syncthreads();
    for (int off = 1; off < SCAN_BS; off <<= 1) {
        int t = (tid >= off) ? s[tid - off] : 0;
        __syncthreads();
        s[tid] += t;
        __syncthreads();
    }
    if (i < N_NODES) offs[i] = s[tid] - v;           // exclusive
    if (tid == SCAN_BS - 1) bsum[blockIdx.x] = s[tid];
}

// exclusive scan of the 196 block sums (single block)
__global__ __launch_bounds__(SCAN_BS)
void scan2_kernel(int* __restrict__ bsum) {
    __shared__ int s[SCAN_BS];
    int tid = threadIdx.x;
    int v = (tid < SCAN_NB) ? bsum[tid] : 0;
    s[tid] = v;
    __syncthreads();
    for (int off = 1; off < SCAN_BS; off <<= 1) {
        int t = (tid >= off) ? s[tid - off] : 0;
        __syncthreads();
        s[tid] += t;
        __syncthreads();
    }
    if (tid < SCAN_NB) bsum[tid] = s[tid] - v;
}

// add block offsets; also init cursor copy and offs[N_NODES]=E
__global__ __launch_bounds__(SCAN_BS)
void scan3_kernel(int* __restrict__ offs, const int* __restrict__ bsum,
                  int* __restrict__ cur) {
    int i = blockIdx.x * SCAN_BS + threadIdx.x;
    if (i < N_NODES) {
        int o = offs[i] + bsum[blockIdx.x];
        offs[i] = o;
        cur[i] = o;
    }
    if (i == 0) offs[N_NODES] = N_EDGES;
}

__global__ __launch_bounds__(256)
void fill_kernel(const int* __restrict__ ei, int* __restrict__ cur,
                 int2* __restrict__ csr) {
    int e = blockIdx.x * blockDim.x + threadIdx.x;
    if (e >= N_EDGES) return;
    int src = ei[e];
    int dst = ei[N_EDGES + e];
    int j = atomicAdd(&cur[dst], 1);
    csr[j] = make_int2(src, e);   // (src node, edge id)
}

// ---------------------------------------------------------------------------
// prep: one thread per (node, o). Computes, for one layer:
//   zw[n][k][o] = sum_i x[n][i] * nnW[k][i*16+o]   (k = 0..7)
//   zw[n][8][o] = sum_i x[n][i] * nnb[i*16+o]      (the per-edge bias term w)
//   rb[n][o]    = bias[o] + sum_i x[n][i] * rootW[i][o]
// x read applies ReLU when reading a previous layer's pre-activation buffer.
// ---------------------------------------------------------------------------
__global__ __launch_bounds__(256)
void prep_kernel(const float* __restrict__ x_in,   // [N,16]
                 const float* __restrict__ nnW,    // [8,256]
                 const float* __restrict__ nnb,    // [256]
                 const float* __restrict__ rootW,  // [16,16]
                 const float* __restrict__ bias,   // [16]
                 float* __restrict__ zw,           // [N,9,16]
                 float* __restrict__ rb,           // [N,16]
                 int apply_relu) {
    int t = blockIdx.x * blockDim.x + threadIdx.x;
    if (t >= N_NODES * HID) return;
    int n = t >> 4;
    int o = t & 15;

    float xv[IN_DIM];
    const float* xr = x_in + n * IN_DIM;
#pragma unroll
    for (int i = 0; i < IN_DIM; ++i) {
        float v = xr[i];
        xv[i] = apply_relu ? fmaxf(v, 0.0f) : v;
    }

    float zk[EDGE_DIM];
#pragma unroll
    for (int k = 0; k < EDGE_DIM; ++k) zk[k] = 0.0f;
    float wv = 0.0f;
    float rv = bias[o];

#pragma unroll
    for (int i = 0; i < IN_DIM; ++i) {
        float xi = xv[i];
#pragma unroll
        for (int k = 0; k < EDGE_DIM; ++k) {
            zk[k] = fmaf(xi, nnW[k * 256 + i * 16 + o], zk[k]);
        }
        wv = fmaf(xi, nnb[i * 16 + o], wv);
        rv = fmaf(xi, rootW[i * 16 + o], rv);
    }

    float* zn = zw + (size_t)n * 144;
#pragma unroll
    for (int k = 0; k < EDGE_DIM; ++k) zn[k * 16 + o] = zk[k];
    zn[128 + o] = wv;
    rb[n * 16 + o] = rv;
}

// ---------------------------------------------------------------------------
// agg: 16 lanes per node (lane = output channel o), 16 nodes per block.
//   acc[o] = rb[n][o] + sum_{edges e->n} ( zw[src][8][o]
//                     + sum_k ea[e][k] * zw[src][k][o] )
// No atomics; single coalesced write per node. All gather loads are
// 64B-contiguous within the 16-lane group.
// ---------------------------------------------------------------------------
__global__ __launch_bounds__(256)
void agg_kernel(const int* __restrict__ offs,     // [N+1]
                const int2* __restrict__ csr,     // [E] (src, eid)
                const float* __restrict__ ea,     // [E,8]
                const float* __restrict__ zw,     // [N,9,16]
                float* __restrict__ buf) {        // in: rb, out: pre-ReLU
    int tid = threadIdx.x;
    int o = tid & 15;
    int n = blockIdx.x * 16 + (tid >> 4);
    if (n >= N_NODES) return;

    float acc = buf[n * HID + o];
    int jb = offs[n], je = offs[n + 1];
    for (int j = jb; j < je; ++j) {
        int2 se = csr[j];
        const float* zp = zw + (size_t)se.x * 144;
        const float4* eap = (const float4*)(ea + (size_t)se.y * EDGE_DIM);
        float4 e0 = eap[0];
        float4 e1 = eap[1];
        acc += zp[128 + o];                       // w term
        acc = fmaf(e0.x, zp[0 * 16 + o], acc);
        acc = fmaf(e0.y, zp[1 * 16 + o], acc);
        acc = fmaf(e0.z, zp[2 * 16 + o], acc);
        acc = fmaf(e0.w, zp[3 * 16 + o], acc);
        acc = fmaf(e1.x, zp[4 * 16 + o], acc);
        acc = fmaf(e1.y, zp[5 * 16 + o], acc);
        acc = fmaf(e1.z, zp[6 * 16 + o], acc);
        acc = fmaf(e1.w, zp[7 * 16 + o], acc);
    }
    buf[n * HID + o] = acc;
}

// ---------------------------------------------------------------------------
// head: one thread per node.
// ---------------------------------------------------------------------------
__global__ __launch_bounds__(256)
void head_kernel(const float* __restrict__ agg,   // [N,16] pre-ReLU
                 const float* __restrict__ gf,    // [8,N]
                 const float* __restrict__ hW,    // [24,1]
                 const float* __restrict__ hb,    // [1]
                 float* __restrict__ out) {       // [N]
    int n = blockIdx.x * blockDim.x + threadIdx.x;
    if (n >= N_NODES) return;
    float acc = hb[0];
    const float* ar = agg + n * HID;
#pragma unroll
    for (int o = 0; o < HID; ++o) acc = fmaf(fmaxf(ar[o], 0.0f), hW[o], acc);
#pragma unroll
    for (int g = 0; g < GRAPH_DIM; ++g) acc = fmaf(gf[g * N_NODES + n], hW[HID + g], acc);
    out[n] = acc;
}

extern "C" void kernel_launch(void* const* d_in, const int* in_sizes, int n_in,
                              void* d_out, int out_size, void* d_ws, size_t ws_size,
                              hipStream_t stream) {
    const float* x     = (const float*)d_in[0];
    const int*   ei    = (const int*)d_in[1];
    const float* ea    = (const float*)d_in[2];
    const float* gf    = (const float*)d_in[3];
    const float* nnW   = (const float*)d_in[4];
    const float* nnb   = (const float*)d_in[5];
    const float* rootW = (const float*)d_in[6];
    const float* bias  = (const float*)d_in[7];
    const float* hW    = (const float*)d_in[8];
    const float* hb    = (const float*)d_in[9];
    float* out = (float*)d_out;

    // workspace layout:
    //   zw:   N*144 f32 = 28.8 MB
    //   bufA: N*16  f32 =  3.2 MB
    //   bufB: N*16  f32 =  3.2 MB
    //   deg:  N     i32
    //   offs: N+1   i32 (padded)
    //   cur:  N     i32
    //   bsum: 256   i32          (~0.6 MB of ints)
    //   csr:  E int2 = 6.4 MB    total ~42.2 MB
    float* zw   = (float*)d_ws;
    float* bufA = zw + (size_t)N_NODES * 144;
    float* bufB = bufA + (size_t)N_NODES * HID;
    int*   deg  = (int*)(bufB + (size_t)N_NODES * HID);
    int*   offs = deg + N_NODES;
    int*   cur  = offs + N_NODES + 8;       // +8 pad keeps alignment
    int*   bsum = cur + N_NODES;
    int2*  csr  = (int2*)(bsum + SCAN_BS);  // int count so far is even -> 8B aligned

    dim3 blk(256);
    dim3 grid_n((N_NODES + 255) / 256);          // 196
    dim3 grid_e((N_EDGES + 255) / 256);          // 3125
    dim3 grid_no((N_NODES * HID + 255) / 256);   // 3125
    dim3 grid_a((N_NODES + 15) / 16);            // 3125 (16 nodes/block)

    // ---- CSR build (once; reused by all 3 layers) ----
    zero_deg_kernel<<<grid_n, blk, 0, stream>>>(deg);
    hist_kernel<<<grid_e, blk, 0, stream>>>(ei, deg);
    scan1_kernel<<<SCAN_NB, SCAN_BS, 0, stream>>>(deg, offs, bsum);
    scan2_kernel<<<1, SCAN_BS, 0, stream>>>(bsum);
    scan3_kernel<<<SCAN_NB, SCAN_BS, 0, stream>>>(offs, bsum, cur);
    fill_kernel<<<grid_e, blk, 0, stream>>>(ei, cur, csr);

    // ---- 3 NNConv layers ----
    const float* xin = x;
    float* bufs[2] = {bufA, bufB};
    for (int l = 0; l < N_LAYERS; ++l) {
        float* buf = bufs[l & 1];
        prep_kernel<<<grid_no, blk, 0, stream>>>(
            xin,
            nnW + (size_t)l * EDGE_DIM * (IN_DIM * HID),
            nnb + (size_t)l * (IN_DIM * HID),
            rootW + (size_t)l * IN_DIM * HID,
            bias + (size_t)l * HID,
            zw, buf, l > 0 ? 1 : 0);
        agg_kernel<<<grid_a, blk, 0, stream>>>(offs, csr, ea, zw, buf);
        xin = buf;
    }
    // layers: l0->bufA, l1->bufB, l2->bufA
    head_kernel<<<grid_n, blk, 0, stream>>>(bufA, gf, hW, hb, out);
}

// Round 8
// 393.271 us; speedup vs baseline: 5.6623x; 1.3102x over previous
//
#include <hip/hip_runtime.h>
#include <hip/hip_fp16.h>

#define N_NODES 50000
#define N_EDGES 800000
#define IN_DIM 16
#define HID 16
#define EDGE_DIM 8
#define GRAPH_DIM 8
#define N_LAYERS 3
#define SCAN_BS 256
#define SCAN_NB ((N_NODES + SCAN_BS - 1) / SCAN_BS)   // 196

__device__ __forceinline__ unsigned pack_h2(float lo, float hi) {
    __half2 h = __floats2half2_rn(lo, hi);
    return *reinterpret_cast<unsigned*>(&h);
}
__device__ __forceinline__ float2 unpack_h2(unsigned u) {
    __half2 h = *reinterpret_cast<__half2*>(&u);
    return __half22float2(h);
}

// ---------------------------------------------------------------------------
// CSR build (once per launch; edge_index is layer-invariant)
// ---------------------------------------------------------------------------
__global__ __launch_bounds__(256)
void zero_deg_kernel(int* __restrict__ deg) {
    int i = blockIdx.x * blockDim.x + threadIdx.x;
    if (i < N_NODES) deg[i] = 0;
}

__global__ __launch_bounds__(256)
void hist_kernel(const int* __restrict__ ei, int* __restrict__ deg) {
    int e = blockIdx.x * blockDim.x + threadIdx.x;
    if (e < N_EDGES) atomicAdd(&deg[ei[N_EDGES + e]], 1);
}

__global__ __launch_bounds__(SCAN_BS)
void scan1_kernel(const int* __restrict__ deg, int* __restrict__ offs,
                  int* __restrict__ bsum) {
    __shared__ int s[SCAN_BS];
    int tid = threadIdx.x;
    int i = blockIdx.x * SCAN_BS + tid;
    int v = (i < N_NODES) ? deg[i] : 0;
    s[tid] = v;
    __syncthreads();
    for (int off = 1; off < SCAN_BS; off <<= 1) {
        int t = (tid >= off) ? s[tid - off] : 0;
        __syncthreads();
        s[tid] += t;
        __syncthreads();
    }
    if (i < N_NODES) offs[i] = s[tid] - v;           // exclusive
    if (tid == SCAN_BS - 1) bsum[blockIdx.x] = s[tid];
}

__global__ __launch_bounds__(SCAN_BS)
void scan2_kernel(int* __restrict__ bsum) {
    __shared__ int s[SCAN_BS];
    int tid = threadIdx.x;
    int v = (tid < SCAN_NB) ? bsum[tid] : 0;
    s[tid] = v;
    __syncthreads();
    for (int off = 1; off < SCAN_BS; off <<= 1) {
        int t = (tid >= off) ? s[tid - off] : 0;
        __syncthreads();
        s[tid] += t;
        __syncthreads();
    }
    if (tid < SCAN_NB) bsum[tid] = s[tid] - v;
}

__global__ __launch_bounds__(SCAN_BS)
void scan3_kernel(int* __restrict__ offs, const int* __restrict__ bsum,
                  int* __restrict__ cur) {
    int i = blockIdx.x * SCAN_BS + threadIdx.x;
    if (i < N_NODES) {
        int o = offs[i] + bsum[blockIdx.x];
        offs[i] = o;
        cur[i] = o;
    }
    if (i == 0) offs[N_NODES] = N_EDGES;
}

// fill: scatter edges into CSR order; also permute ea into CSR order as fp16x8
__global__ __launch_bounds__(256)
void fill_kernel(const int* __restrict__ ei, const float* __restrict__ ea,
                 int* __restrict__ cur, int* __restrict__ csr_src,
                 uint4* __restrict__ ea_h) {
    int e = blockIdx.x * blockDim.x + threadIdx.x;
    if (e >= N_EDGES) return;
    int src = ei[e];
    int dst = ei[N_EDGES + e];
    const float4* eap = (const float4*)(ea + (size_t)e * EDGE_DIM);
    float4 e0 = eap[0];
    float4 e1 = eap[1];
    uint4 rec;
    rec.x = pack_h2(e0.x, e0.y);
    rec.y = pack_h2(e0.z, e0.w);
    rec.z = pack_h2(e1.x, e1.y);
    rec.w = pack_h2(e1.z, e1.w);
    int j = atomicAdd(&cur[dst], 1);
    csr_src[j] = src;
    ea_h[j] = rec;
}

// ---------------------------------------------------------------------------
// prep: one thread per (node, o). fp16-packed zw:
//   zw_h[n][kp][o] = half2(z[2kp], z[2kp+1])   kp = 0..3
//   zw_h[n][4][o]  = half2(w, 0)
//   rb[n][o]       = bias[o] + sum_i x[n][i]*rootW[i][o]
// ---------------------------------------------------------------------------
__global__ __launch_bounds__(256)
void prep_kernel(const float* __restrict__ x_in,   // [N,16]
                 const float* __restrict__ nnW,    // [8,256]
                 const float* __restrict__ nnb,    // [256]
                 const float* __restrict__ rootW,  // [16,16]
                 const float* __restrict__ bias,   // [16]
                 unsigned* __restrict__ zw_h,      // [N,5,16] half2
                 float* __restrict__ rb,           // [N,16]
                 int apply_relu) {
    int t = blockIdx.x * blockDim.x + threadIdx.x;
    if (t >= N_NODES * HID) return;
    int n = t >> 4;
    int o = t & 15;

    float xv[IN_DIM];
    const float* xr = x_in + n * IN_DIM;
#pragma unroll
    for (int i = 0; i < IN_DIM; ++i) {
        float v = xr[i];
        xv[i] = apply_relu ? fmaxf(v, 0.0f) : v;
    }

    float zk[EDGE_DIM];
#pragma unroll
    for (int k = 0; k < EDGE_DIM; ++k) zk[k] = 0.0f;
    float wv = 0.0f;
    float rv = bias[o];

#pragma unroll
    for (int i = 0; i < IN_DIM; ++i) {
        float xi = xv[i];
#pragma unroll
        for (int k = 0; k < EDGE_DIM; ++k) {
            zk[k] = fmaf(xi, nnW[k * 256 + i * 16 + o], zk[k]);
        }
        wv = fmaf(xi, nnb[i * 16 + o], wv);
        rv = fmaf(xi, rootW[i * 16 + o], rv);
    }

    unsigned* zn = zw_h + (size_t)n * 80;
#pragma unroll
    for (int kp = 0; kp < 4; ++kp) zn[kp * 16 + o] = pack_h2(zk[2 * kp], zk[2 * kp + 1]);
    zn[64 + o] = pack_h2(wv, 0.0f);
    rb[n * 16 + o] = rv;
}

// ---------------------------------------------------------------------------
// agg: 16 lanes per node (lane = channel o), 16 nodes per block.
//   acc[o] += sum_edges ( w[src][o] + sum_k ea[k]*z[src][k][o] )
// zw gather: 5 x 64B lines/edge; csr stream sequential 20B/edge; no atomics.
// ---------------------------------------------------------------------------
__global__ __launch_bounds__(256)
void agg_kernel(const int* __restrict__ offs,       // [N+1]
                const int* __restrict__ csr_src,    // [E]
                const uint4* __restrict__ ea_h,     // [E] fp16x8
                const unsigned* __restrict__ zw_h,  // [N,5,16] half2
                float* __restrict__ buf) {          // in: rb, out: pre-ReLU
    int tid = threadIdx.x;
    int o = tid & 15;
    int n = blockIdx.x * 16 + (tid >> 4);
    if (n >= N_NODES) return;

    float acc = buf[n * HID + o];
    int jb = offs[n], je = offs[n + 1];
    for (int j = jb; j < je; ++j) {
        int src = csr_src[j];
        uint4 rec = ea_h[j];
        const unsigned* zp = zw_h + (size_t)src * 80;
        unsigned q0 = zp[o];
        unsigned q1 = zp[16 + o];
        unsigned q2 = zp[32 + o];
        unsigned q3 = zp[48 + o];
        unsigned q4 = zp[64 + o];
        float2 e01 = unpack_h2(rec.x);
        float2 e23 = unpack_h2(rec.y);
        float2 e45 = unpack_h2(rec.z);
        float2 e67 = unpack_h2(rec.w);
        float2 z01 = unpack_h2(q0);
        float2 z23 = unpack_h2(q1);
        float2 z45 = unpack_h2(q2);
        float2 z67 = unpack_h2(q3);
        float2 w_  = unpack_h2(q4);
        acc += w_.x;
        acc = fmaf(e01.x, z01.x, acc);
        acc = fmaf(e01.y, z01.y, acc);
        acc = fmaf(e23.x, z23.x, acc);
        acc = fmaf(e23.y, z23.y, acc);
        acc = fmaf(e45.x, z45.x, acc);
        acc = fmaf(e45.y, z45.y, acc);
        acc = fmaf(e67.x, z67.x, acc);
        acc = fmaf(e67.y, z67.y, acc);
    }
    buf[n * HID + o] = acc;
}

// ---------------------------------------------------------------------------
// head: one thread per node.
// ---------------------------------------------------------------------------
__global__ __launch_bounds__(256)
void head_kernel(const float* __restrict__ agg,   // [N,16] pre-ReLU
                 const float* __restrict__ gf,    // [8,N]
                 const float* __restrict__ hW,    // [24,1]
                 const float* __restrict__ hb,    // [1]
                 float* __restrict__ out) {       // [N]
    int n = blockIdx.x * blockDim.x + threadIdx.x;
    if (n >= N_NODES) return;
    float acc = hb[0];
    const float* ar = agg + n * HID;
#pragma unroll
    for (int o = 0; o < HID; ++o) acc = fmaf(fmaxf(ar[o], 0.0f), hW[o], acc);
#pragma unroll
    for (int g = 0; g < GRAPH_DIM; ++g) acc = fmaf(gf[g * N_NODES + n], hW[HID + g], acc);
    out[n] = acc;
}

extern "C" void kernel_launch(void* const* d_in, const int* in_sizes, int n_in,
                              void* d_out, int out_size, void* d_ws, size_t ws_size,
                              hipStream_t stream) {
    const float* x     = (const float*)d_in[0];
    const int*   ei    = (const int*)d_in[1];
    const float* ea    = (const float*)d_in[2];
    const float* gf    = (const float*)d_in[3];
    const float* nnW   = (const float*)d_in[4];
    const float* nnb   = (const float*)d_in[5];
    const float* rootW = (const float*)d_in[6];
    const float* bias  = (const float*)d_in[7];
    const float* hW    = (const float*)d_in[8];
    const float* hb    = (const float*)d_in[9];
    float* out = (float*)d_out;

    // workspace layout (~39 MB):
    //   zw_h:   N*80 u32  = 16.0 MB  (fp16-packed z rows + w row)
    //   ea_h:   E uint4   = 12.8 MB  (fp16x8 edge attrs, CSR order)
    //   bufA:   N*16 f32  =  3.2 MB
    //   bufB:   N*16 f32  =  3.2 MB
    //   csr_src E i32     =  3.2 MB
    //   deg/offs/cur/bsum ~  0.6 MB
    unsigned* zw_h = (unsigned*)d_ws;
    uint4* ea_h    = (uint4*)(zw_h + (size_t)N_NODES * 80);   // offset 16MB, 16B aligned
    float* bufA    = (float*)(ea_h + N_EDGES);
    float* bufB    = bufA + (size_t)N_NODES * HID;
    int* csr_src   = (int*)(bufB + (size_t)N_NODES * HID);
    int* deg       = csr_src + N_EDGES;
    int* offs      = deg + N_NODES;
    int* cur       = offs + N_NODES + 8;
    int* bsum      = cur + N_NODES;

    dim3 blk(256);
    dim3 grid_n((N_NODES + 255) / 256);          // 196
    dim3 grid_e((N_EDGES + 255) / 256);          // 3125
    dim3 grid_no((N_NODES * HID + 255) / 256);   // 3125
    dim3 grid_a((N_NODES + 15) / 16);            // 3125 (16 nodes/block)

    // ---- CSR build (once; reused by all 3 layers) ----
    zero_deg_kernel<<<grid_n, blk, 0, stream>>>(deg);
    hist_kernel<<<grid_e, blk, 0, stream>>>(ei, deg);
    scan1_kernel<<<SCAN_NB, SCAN_BS, 0, stream>>>(deg, offs, bsum);
    scan2_kernel<<<1, SCAN_BS, 0, stream>>>(bsum);
    scan3_kernel<<<SCAN_NB, SCAN_BS, 0, stream>>>(offs, bsum, cur);
    fill_kernel<<<grid_e, blk, 0, stream>>>(ei, ea, cur, csr_src, ea_h);

    // ---- 3 NNConv layers ----
    const float* xin = x;
    float* bufs[2] = {bufA, bufB};
    for (int l = 0; l < N_LAYERS; ++l) {
        float* buf = bufs[l & 1];
        prep_kernel<<<grid_no, blk, 0, stream>>>(
            xin,
            nnW + (size_t)l * EDGE_DIM * (IN_DIM * HID),
            nnb + (size_t)l * (IN_DIM * HID),
            rootW + (size_t)l * IN_DIM * HID,
            bias + (size_t)l * HID,
            zw_h, buf, l > 0 ? 1 : 0);
        agg_kernel<<<grid_a, blk, 0, stream>>>(offs, csr_src, ea_h, zw_h, buf);
        xin = buf;
    }
    // layers: l0->bufA, l1->bufB, l2->bufA
    head_kernel<<<grid_n, blk, 0, stream>>>(bufA, gf, hW, hb, out);
}